// Round 5
// baseline (128.216 us; speedup 1.0000x reference)
//
#include <hip/hip_runtime.h>

// B=256, C=2048, H*W=128, NUM_CLASSES=10000
// Outputs (fp32, concat): logits[256*10000], logits[256*10000],
//                         neck_feat[256*2048], new_weight[256] (== 1.0 analytically)
// targets are dead.

#define OUT1_OFF (256 * 10000)
#define FEAT_OFF (2 * 256 * 10000)
#define NW_OFF   (2 * 256 * 10000 + 256 * 2048)

typedef __attribute__((ext_vector_type(4))) float f32x4;
typedef __attribute__((ext_vector_type(8))) short bf16x8;
typedef __attribute__((ext_vector_type(4))) unsigned int u32x4;

__device__ inline unsigned pk2bf(float lo, float hi) {
    unsigned a = __float_as_uint(lo), b = __float_as_uint(hi);
    unsigned ra = (a + 0x7FFFu + ((a >> 16) & 1u)) >> 16;
    unsigned rb = (b + 0x7FFFu + ((b >> 16) & 1u)) & 0xFFFF0000u;
    return ra | rb;
}

// ---------------------------------------------------------------------------
// Kernel 1 (pool): EXACT round-2 structure (best measured). 32768 blocks x
// 256 thr; each 32-lane group reduces 2 consecutive rows with fully
// contiguous 1KB wave reads. Writes feat fp32 + wsA bf16 fragment-major:
// elem (m=b,k=c) at chunk ((b>>4)*256 + (c>>3))*16 + (b&15), u32 word (c&7)>>1.
// ---------------------------------------------------------------------------
__global__ __launch_bounds__(256) void pool_kernel(
    const float* __restrict__ f, float* __restrict__ out,
    unsigned int* __restrict__ wsA32) {
    int tid = threadIdx.x;
    int g = tid >> 5;
    int l = tid & 31;
    int r0 = blockIdx.x * 16 + g * 2;  // rows r0, r0+1 (r0 even)
    const f32x4* s0 = (const f32x4*)(f + (size_t)r0 * 128);
    f32x4 v0 = s0[l];
    f32x4 v1 = s0[l + 32];
    float a = v0[0] + v0[1] + v0[2] + v0[3];
    float b = v1[0] + v1[1] + v1[2] + v1[3];
#pragma unroll
    for (int off = 16; off >= 1; off >>= 1) {
        a += __shfl_xor(a, off);
        b += __shfl_xor(b, off);
    }
    if (l == 0) {
        float m0 = a * (1.0f / 128.0f), m1 = b * (1.0f / 128.0f);
        float2 fv; fv.x = m0; fv.y = m1;
        *(float2*)&out[FEAT_OFF + r0] = fv;
        int bb = r0 >> 11, c = r0 & 2047;
        int chunk = ((bb >> 4) * 256 + (c >> 3)) * 16 + (bb & 15);
        wsA32[chunk * 4 + ((c & 7) >> 1)] = pk2bf(m0, m1);
    }
    if (blockIdx.x == 0) out[NW_OFF + tid] = 1.0f;
}

// ---------------------------------------------------------------------------
// Kernel 2 (GEMM): barrier-free, zero-LDS. logits = A(256x2048 bf16, ws
// fragment-major) * W(10000x2048 fp32->bf16 on the fly)^T.
// 157 blocks x 512 thr = 8 waves (4m x 2n), wave tile 64x32 (4x2 frags of
// 16x16x32). Each wave loads its own fragments: A per-lane 16B chunks (1KB
// contiguous per wave instr, L2-resident), B per-lane 2xf32x4 directly in
// MFMA fragment layout. Depth-2 register pipeline (X/Y), manually unrolled
// x2 so all indexing is static. No s_barrier -> no vmcnt(0) drains; waves
// slip freely; wm-waves sharing wn dedup W reads through L1.
// ---------------------------------------------------------------------------
__global__ __launch_bounds__(512) void gemm_kernel(
    const u32x4* __restrict__ A16, const float* __restrict__ W,
    float* __restrict__ out) {
    int tid = threadIdx.x;
    int n0 = blockIdx.x * 64;
    int wid = tid >> 6, lane = tid & 63;
    int wm = wid >> 1, wn = wid & 1;
    int r = lane & 15, q = lane >> 4;

    // A: chunk(m,k) = ((m>>4)*256 + (k>>3))*16 + (m&15); lane (r,q) frag
    // (i,ks) at mt*4096 + kt*128 + ks*64 + q*16 + r, mt = wm*4+i.
    const u32x4* paBase = A16 + q * 16 + r;
    int wmBase = wm * 16384;

    // B: lane (r,q), frag j: row n0+(wn*2+j)*16+r, floats kt*64+ks*32+q*8..+7
    int row0 = n0 + wn * 32 + r;
    if (row0 > 9999) row0 = 9999;  // clamp; stores predicated
    int row1 = row0 + 16;
    if (row1 > 9999) row1 = 9999;
    const f32x4* pB0 = (const f32x4*)(W + (size_t)row0 * 2048) + q * 2;
    const f32x4* pB1 = (const f32x4*)(W + (size_t)row1 * 2048) + q * 2;

    f32x4 acc[4][2];
#pragma unroll
    for (int i = 0; i < 4; ++i)
#pragma unroll
        for (int j = 0; j < 2; ++j) acc[i][j] = (f32x4){0.f, 0.f, 0.f, 0.f};

    u32x4 Xa0, Xa1, Xa2, Xa3, Xa4, Xa5, Xa6, Xa7;
    f32x4 Xb0, Xb1, Xb2, Xb3, Xb4, Xb5, Xb6, Xb7;
    u32x4 Ya0, Ya1, Ya2, Ya3, Ya4, Ya5, Ya6, Ya7;
    f32x4 Yb0, Yb1, Yb2, Yb3, Yb4, Yb5, Yb6, Yb7;

#define ISSUE(S, kt)                                      \
    {                                                     \
        const u32x4* pa = paBase + (kt) * 128;            \
        S##a0 = pa[wmBase];                               \
        S##a1 = pa[wmBase + 64];                          \
        S##a2 = pa[wmBase + 4096];                        \
        S##a3 = pa[wmBase + 4160];                        \
        S##a4 = pa[wmBase + 8192];                        \
        S##a5 = pa[wmBase + 8256];                        \
        S##a6 = pa[wmBase + 12288];                       \
        S##a7 = pa[wmBase + 12352];                       \
        S##b0 = pB0[(kt)*16];                             \
        S##b1 = pB0[(kt)*16 + 1];                         \
        S##b2 = pB0[(kt)*16 + 8];                         \
        S##b3 = pB0[(kt)*16 + 9];                         \
        S##b4 = pB1[(kt)*16];                             \
        S##b5 = pB1[(kt)*16 + 1];                         \
        S##b6 = pB1[(kt)*16 + 8];                         \
        S##b7 = pB1[(kt)*16 + 9];                         \
    }

#define CVT(bv, p0, p1)                  \
    {                                    \
        u32x4 t;                         \
        t.x = pk2bf(p0[0], p0[1]);       \
        t.y = pk2bf(p0[2], p0[3]);       \
        t.z = pk2bf(p1[0], p1[1]);       \
        t.w = pk2bf(p1[2], p1[3]);       \
        bv = *(bf16x8*)&t;               \
    }

#define MF(i, a_, bv, j)                                       \
    acc[i][j] = __builtin_amdgcn_mfma_f32_16x16x32_bf16(       \
        *(bf16x8*)&a_, bv, acc[i][j], 0, 0, 0)

#define COMPUTE(S)                                                          \
    {                                                                       \
        bf16x8 bv;                                                          \
        CVT(bv, S##b0, S##b1); /* j=0 ks=0 */                               \
        MF(0, S##a0, bv, 0); MF(1, S##a2, bv, 0);                           \
        MF(2, S##a4, bv, 0); MF(3, S##a6, bv, 0);                           \
        CVT(bv, S##b2, S##b3); /* j=0 ks=1 */                               \
        MF(0, S##a1, bv, 0); MF(1, S##a3, bv, 0);                           \
        MF(2, S##a5, bv, 0); MF(3, S##a7, bv, 0);                           \
        CVT(bv, S##b4, S##b5); /* j=1 ks=0 */                               \
        MF(0, S##a0, bv, 1); MF(1, S##a2, bv, 1);                           \
        MF(2, S##a4, bv, 1); MF(3, S##a6, bv, 1);                           \
        CVT(bv, S##b6, S##b7); /* j=1 ks=1 */                               \
        MF(0, S##a1, bv, 1); MF(1, S##a3, bv, 1);                           \
        MF(2, S##a5, bv, 1); MF(3, S##a7, bv, 1);                           \
    }

    // depth-2 register pipeline
    ISSUE(X, 0);
    ISSUE(Y, 1);
    for (int kt = 0; kt < 30; kt += 2) {
        COMPUTE(X);
        ISSUE(X, kt + 2);
        COMPUTE(Y);
        ISSUE(Y, kt + 3);
    }
    COMPUTE(X);
    COMPUTE(Y);

    // ---- epilogue: C and C*SCALE (SCALE=1) ----
#pragma unroll
    for (int i = 0; i < 4; ++i)
#pragma unroll
        for (int j = 0; j < 2; ++j) {
            int n = n0 + (wn * 2 + j) * 16 + r;
            if (n < 10000) {
                int mbase = (wm * 4 + i) * 16 + q * 4;
#pragma unroll
                for (int qq = 0; qq < 4; ++qq) {
                    float v = acc[i][j][qq];
                    size_t off = (size_t)(mbase + qq) * 10000 + n;
                    out[off] = v;
                    out[OUT1_OFF + off] = v;
                }
            }
        }
#undef ISSUE
#undef CVT
#undef MF
#undef COMPUTE
}

extern "C" void kernel_launch(void* const* d_in, const int* in_sizes, int n_in,
                              void* d_out, int out_size, void* d_ws, size_t ws_size,
                              hipStream_t stream) {
    const float* feats = (const float*)d_in[0];
    // d_in[1] = targets (int32) — dead (new_weight == ones analytically)
    const float* weight = (const float*)d_in[2];
    float* out = (float*)d_out;

    pool_kernel<<<32768, 256, 0, stream>>>(feats, out, (unsigned int*)d_ws);
    gemm_kernel<<<157, 512, 0, stream>>>((const u32x4*)d_ws, weight, out);
}